// Round 12
// baseline (743.242 us; speedup 1.0000x reference)
//
#include <hip/hip_runtime.h>
#include <hip/hip_bf16.h>

#define DI __device__ __forceinline__

typedef __attribute__((ext_vector_type(8))) short short8;
typedef __attribute__((ext_vector_type(4))) float f32x4;

DI unsigned short f2bf(float f) {
    union { float f; unsigned int u; } v; v.f = f;
    unsigned int r = v.u + 0x7FFFu + ((v.u >> 16) & 1u);
    return (unsigned short)(r >> 16);
}
DI float bf2f(unsigned short h) {
    union { unsigned int u; float f; } v; v.u = ((unsigned int)h) << 16;
    return v.f;
}

#define GLD16(g, l) __builtin_amdgcn_global_load_lds( \
    (const __attribute__((address_space(1))) void*)(g), \
    (__attribute__((address_space(3))) void*)(l), 16, 0, 0)

// ---------------------------------------------------------------------------
// 256x256 4-phase NT GEMM, BK=64, 8 waves (2Mx4N), 128KiB LDS.
// C[i][j] = sum_k A[i][k] * Bt[j][k]
// Core schedule = r11 (verified 697us best): per phase {12 ds_reads ->
// compiler-interleaved 32 MFMA (setprio) -> vmcnt(8) -> barrier}; peel
// drains 8->4->0.  Swizzle LDS[r][p] = G[r][p ^ ((r>>1)&3)] (conflict-free).
// XCD chunking (bijective, nwg%8==0): lin -> (lin&7)*(nwg/8)+(lin>>3).
// NT full-line stores for write-once outputs.
// r12 NEW: QKV group 2 (V) writes its output DIRECTLY TRANSPOSED as
// Vt[b][c][m] via a transposed LDS epilogue pass (tile rows = exactly half a
// batch: b=tm>>1, m_base=(tm&1)*256) -> the separate transpose_v kernel and
// its 168MB of HBM traffic are eliminated.
// EPI: 0 = +bias->bf16(NT), 1 = *scale+mask->bf16, 2 = bf16, 3 = +bias->f32(NT)
// QKV=1: tn in [0,15); g = tn/5 selects Bt/Cout/bias; g==2 -> Vt epilogue.
// Requires: M%256==0, N%256==0, K%128==0, K>=256.
// ---------------------------------------------------------------------------
template<int EPI, int QKV>
__global__ __launch_bounds__(512, 2) void gemm256(
    const unsigned short* __restrict__ A, const unsigned short* __restrict__ Bt,
    void* __restrict__ Cout, const float* __restrict__ bias,
    const float* __restrict__ bias1, const float* __restrict__ bias2,
    const int* __restrict__ mask, int K, int lda, int ldb, int ldc,
    long sA, long sB, long sC, long sM, float scale)
{
    __shared__ unsigned short lds[65536];   // 128 KiB

    // XCD-chunked bijective remap of the flattened grid (nwg % 8 == 0)
    const unsigned gx = gridDim.x, gy = gridDim.y;
    unsigned lin = blockIdx.x + gx * (blockIdx.y + gy * blockIdx.z);
    const unsigned nwg = gx * gy * gridDim.z;
    lin = (lin & 7u) * (nwg >> 3) + (lin >> 3);
    int tn = lin % gx;
    const int tm = (lin / gx) % gy;
    const int z = lin / (gx * gy);

    int gsel = 0;
    if (QKV) {
        gsel = tn / 5; tn -= gsel * 5;
        Bt += (size_t)gsel * sB;
        Cout = (void*)((unsigned short*)Cout + (size_t)gsel * sC);
        if (gsel == 1) bias = bias1; else if (gsel == 2) bias = bias2;
    }

    const unsigned short* Ab = A + (long)z * sA + (size_t)(tm * 256) * lda;
    const unsigned short* Bb = Bt + (QKV ? 0 : (long)z * sB) + (size_t)(tn * 256) * ldb;

    const int tid = threadIdx.x, wave = tid >> 6, l = tid & 63;
    const int wr = wave >> 2, wc = wave & 3;    // 2 x 4 wave grid

    const int srow = wave * 32 + (l >> 2);
    const int schunk = ((l & 3) ^ ((l >> 3) & 3)) * 8;
    const unsigned short* agS = Ab + (size_t)srow * lda + schunk;
    const unsigned short* bgS = Bb + (size_t)srow * ldb + schunk;
    unsigned short* ldsA0 = &lds[wave * 1024];
    unsigned short* ldsB0 = &lds[8192 + wave * 1024];

    const int rl = l & 15;
    const int cl8 = ((l >> 4) ^ ((l >> 1) & 3)) * 8;
    const int aoff = (wr * 128 + rl) * 32 + cl8;
    const int boff = 8192 + (wc * 64 + rl) * 32 + cl8;

#define REGOFF(buf, h) (((buf) * 2 + (h)) * 16384)
#define SA(t, h, buf) { const unsigned short* g_ = agS + (size_t)((t) * 64 + (h) * 32); \
    GLD16(g_, ldsA0 + REGOFF(buf, h)); \
    GLD16(g_ + (size_t)16 * lda, ldsA0 + REGOFF(buf, h) + 512); }
#define SB(t, h, buf) { const unsigned short* g_ = bgS + (size_t)((t) * 64 + (h) * 32); \
    GLD16(g_, ldsB0 + REGOFF(buf, h)); \
    GLD16(g_ + (size_t)16 * ldb, ldsB0 + REGOFF(buf, h) + 512); }

    f32x4 acc[8][4] = {};

    // One phase: consume region (buf,h) fully (32 MFMA), stage next, 1 barrier.
#define PHASE(buf, h, STG, VMW) { \
    short8 af[8], bfv[4]; \
    _Pragma("unroll") for (int i = 0; i < 4; ++i) \
        af[i] = *(const short8*)&lds[REGOFF(buf, h) + aoff + i * 512]; \
    _Pragma("unroll") for (int n = 0; n < 4; ++n) \
        bfv[n] = *(const short8*)&lds[REGOFF(buf, h) + boff + n * 512]; \
    _Pragma("unroll") for (int i = 4; i < 8; ++i) \
        af[i] = *(const short8*)&lds[REGOFF(buf, h) + aoff + i * 512]; \
    STG; \
    __builtin_amdgcn_s_setprio(1); \
    _Pragma("unroll") for (int i = 0; i < 8; ++i) \
        _Pragma("unroll") for (int n = 0; n < 4; ++n) \
            acc[i][n] = __builtin_amdgcn_mfma_f32_16x16x32_bf16( \
                af[i], bfv[n], acc[i][n], 0, 0, 0); \
    __builtin_amdgcn_s_setprio(0); \
    asm volatile("s_waitcnt " VMW ::: "memory"); \
    __builtin_amdgcn_s_barrier(); \
  }

    // prologue: buf0h0, buf0h1, buf1h0 (12 loads); wait buf0h0 (oldest 4)
    SA(0, 0, 0); SB(0, 0, 0); SA(0, 1, 0); SB(0, 1, 0); SA(1, 0, 1); SB(1, 0, 1);
    asm volatile("s_waitcnt vmcnt(8)" ::: "memory");
    __builtin_amdgcn_s_barrier();

    const int NI = K >> 7;          // iterations, 2 K-tiles (BK=64) each
    for (int j = 0; j < NI - 1; ++j) {
        const int t = 2 * j;
        PHASE(0, 0, SA(t + 1, 1, 1) SB(t + 1, 1, 1), "vmcnt(8)")
        PHASE(0, 1, SA(t + 2, 0, 0) SB(t + 2, 0, 0), "vmcnt(8)")
        PHASE(1, 0, SA(t + 2, 1, 0) SB(t + 2, 1, 0), "vmcnt(8)")
        PHASE(1, 1, SA(t + 3, 0, 1) SB(t + 3, 0, 1), "vmcnt(8)")
    }
    {   // peeled last iteration: stage only tile 2NI-1 h1; drain 8->4->0
        const int t = 2 * (NI - 1);
        PHASE(0, 0, SA(t + 1, 1, 1) SB(t + 1, 1, 1), "vmcnt(8)")
        PHASE(0, 1, ((void)0),                       "vmcnt(4)")
        PHASE(1, 0, ((void)0),                       "vmcnt(0)")
        PHASE(1, 1, ((void)0),                       "vmcnt(0)")
    }
#undef PHASE
#undef SA
#undef SB
#undef REGOFF

    // ---------------- epilogue ----------------
    const long cb = QKV ? 0 : (long)z * sC;
    const int row0 = tm * 256 + wr * 128 + (l >> 4) * 4;
    const int col0 = tn * 256 + wc * 64 + rl;

    if (QKV && gsel == 2) {
        // V group: write DIRECTLY TRANSPOSED as Vt[b][c][m] (b=tm>>1,
        // m_base=(tm&1)*256). Two passes over 128-col halves: transposed LDS
        // dump [c][m] then 16B NT row stores (256 m = 512B = 8 full lines).
        float b4[4];
        #pragma unroll
        for (int n = 0; n < 4; ++n) b4[n] = bias[col0 + n * 16];
        unsigned short* vout = (unsigned short*)Cout;
        const int bz = tm >> 1, mb = (tm & 1) * 256;
        #pragma unroll
        for (int hc = 0; hc < 2; ++hc) {
            if ((wc >> 1) == hc) {
                #pragma unroll
                for (int mi = 0; mi < 8; ++mi)
                    #pragma unroll
                    for (int n = 0; n < 4; ++n)
                        #pragma unroll
                        for (int r = 0; r < 4; ++r) {
                            const int lc = (wc & 1) * 64 + n * 16 + rl;
                            const int m  = wr * 128 + mi * 16 + ((l >> 4) << 2) + r;
                            lds[lc * 264 + m] = f2bf(acc[mi][n][r] + b4[n]);
                        }
            }
            __syncthreads();
            {
                const int cl = tid >> 2, seg = tid & 3;
                unsigned short* dst = vout + (size_t)bz * 655360
                    + (size_t)(tn * 256 + hc * 128 + cl) * 512 + mb + seg * 64;
                const unsigned short* srcl = &lds[cl * 264 + seg * 64];
                #pragma unroll
                for (int i = 0; i < 8; ++i)
                    __builtin_nontemporal_store(*(const short8*)(srcl + i * 8),
                                                (short8*)(dst + i * 8));
            }
            __syncthreads();
        }
    } else if (EPI == 0) {
        // LDS-transpose + 16B nontemporal stores (full-line NT, no L3 fill)
        float b4[4];
        #pragma unroll
        for (int n = 0; n < 4; ++n) b4[n] = bias[col0 + n * 16];
        unsigned short* gout = (unsigned short*)Cout;
        #pragma unroll
        for (int half = 0; half < 2; ++half) {
            if (wr == half) {
                #pragma unroll
                for (int mi = 0; mi < 8; ++mi)
                    #pragma unroll
                    for (int n = 0; n < 4; ++n)
                        #pragma unroll
                        for (int r = 0; r < 4; ++r) {
                            const int lr = mi * 16 + ((l >> 4) << 2) + r;
                            const int lc = wc * 64 + n * 16 + rl;
                            lds[lr * 264 + lc] = f2bf(acc[mi][n][r] + b4[n]);
                        }
            }
            __syncthreads();
            const long rbase = (long)(tm * 256 + half * 128);
            #pragma unroll
            for (int rr = 0; rr < 8; ++rr) {
                const int row = rr * 16 + (tid >> 5);
                const int ch = tid & 31;
                short8 vv = *(const short8*)&lds[row * 264 + ch * 8];
                __builtin_nontemporal_store(vv,
                    (short8*)&gout[(rbase + row) * (size_t)ldc + tn * 256 + ch * 8]);
            }
            __syncthreads();
        }
    } else {
        #pragma unroll
        for (int mi = 0; mi < 8; ++mi) {
            #pragma unroll
            for (int n = 0; n < 4; ++n) {
                #pragma unroll
                for (int r = 0; r < 4; ++r) {
                    const int row = row0 + mi * 16 + r;
                    const int col = col0 + n * 16;
                    float v = acc[mi][n][r];
                    if (EPI == 3) v += bias[col];
                    if (EPI == 1) {
                        v *= scale;
                        if (mask[(long)z * sM + (long)row * ldc + col] == 0)
                            v = -1e20f * scale;
                    }
                    if (EPI == 3)   // f32: 16 lanes x 4B = full 64B line -> NT ok
                        __builtin_nontemporal_store(v, &((float*)Cout)[cb + (long)row * ldc + col]);
                    else
                        ((unsigned short*)Cout)[cb + (long)row * ldc + col] = f2bf(v);
                }
            }
        }
    }
}

// ---------------------------------------------------------------------------
// Transpose+cast the four 1280x1280 f32 weights -> Wt[j][k] bf16
// ---------------------------------------------------------------------------
__global__ void transpose_w(const float* __restrict__ Wq, const float* __restrict__ Wk,
                            const float* __restrict__ Wv, const float* __restrict__ Wr,
                            unsigned short* __restrict__ Wt)
{
    const float* W = blockIdx.z == 0 ? Wq : blockIdx.z == 1 ? Wk : blockIdx.z == 2 ? Wv : Wr;
    unsigned short* dst = Wt + (size_t)blockIdx.z * 1280 * 1280;
    __shared__ float T[64][65];
    const int j0 = blockIdx.x * 64, k0 = blockIdx.y * 64;
    const int tid = threadIdx.x;
    for (int it = 0; it < 16; ++it) {
        int idx = it * 256 + tid;
        int r = idx >> 6, c = idx & 63;
        T[r][c] = W[(size_t)(k0 + r) * 1280 + j0 + c];
    }
    __syncthreads();
    for (int it = 0; it < 16; ++it) {
        int idx = it * 256 + tid;
        int r = idx >> 6, c = idx & 63;
        dst[(size_t)(j0 + r) * 1280 + k0 + c] = f2bf(T[c][r]);
    }
}

// ---------------------------------------------------------------------------
// Cast x f32 -> bf16, vectorized
// ---------------------------------------------------------------------------
__global__ void cast_x(const float* __restrict__ x, unsigned short* __restrict__ xb, long n)
{
    long i = ((long)blockIdx.x * 256 + threadIdx.x) * 8;
    if (i + 8 > n) return;
    const float4* p = (const float4*)(x + i);
    float4 a = p[0], b = p[1];
    unsigned short o[8] = { f2bf(a.x), f2bf(a.y), f2bf(a.z), f2bf(a.w),
                            f2bf(b.x), f2bf(b.y), f2bf(b.z), f2bf(b.w) };
    *(short8*)(xb + i) = *(short8*)o;
}

// ---------------------------------------------------------------------------
// Row softmax of scaled+masked scores S'[b][m][n] (bf16) and transposed write
// Pt[b][n][m] = softmax_row(S')[m][n].  One block per (64-row strip, batch).
// ---------------------------------------------------------------------------
#define SMS 514
__global__ void softmax_t(const unsigned short* __restrict__ S, unsigned short* __restrict__ Pt)
{
    __shared__ unsigned short T[64 * SMS];
    __shared__ float rmax[64], rinv[64];
    const int b = blockIdx.y, mb = blockIdx.x * 64;
    const int tid = threadIdx.x, lane = tid & 63, wave = tid >> 6;
    const unsigned short* src = S + ((size_t)b * 512 + mb) * 512;

    for (int rr = 0; rr < 16; ++rr) {
        int r = rr * 4 + wave;
        const unsigned int* s = (const unsigned int*)(src + (size_t)r * 512);
        unsigned int* t = (unsigned int*)&T[r * SMS];
        #pragma unroll
        for (int j = 0; j < 4; ++j) t[lane + j * 64] = s[lane + j * 64];
    }
    __syncthreads();

    {   // row stats: 4 threads per row
        int r = tid >> 2, q = tid & 3;
        const unsigned short* row = &T[r * SMS + q * 128];
        float mx = -3.0e38f;
        for (int i = 0; i < 128; ++i) mx = fmaxf(mx, bf2f(row[i]));
        mx = fmaxf(mx, __shfl_xor(mx, 1));
        mx = fmaxf(mx, __shfl_xor(mx, 2));
        float s = 0.f;
        for (int i = 0; i < 128; ++i) s += expf(bf2f(row[i]) - mx);
        s += __shfl_xor(s, 1);
        s += __shfl_xor(s, 2);
        if (q == 0) { rmax[r] = mx; rinv[r] = 1.0f / s; }
    }
    __syncthreads();

    {   // transposed write: lane -> m, groups of 64 -> n
        int m = tid & 63, nq = tid >> 6;
        float mxm = rmax[m], rim = rinv[m];
        unsigned short* dst = Pt + (size_t)b * 512 * 512 + mb + m;
        for (int it = 0; it < 128; ++it) {
            int n = it * 4 + nq;
            float v = expf(bf2f(T[m * SMS + n]) - mxm) * rim;
            dst[(size_t)n * 512] = f2bf(v);
        }
    }
}

// ---------------------------------------------------------------------------
extern "C" void kernel_launch(void* const* d_in, const int* in_sizes, int n_in,
                              void* d_out, int out_size, void* d_ws, size_t ws_size,
                              hipStream_t stream)
{
    const float* x   = (const float*)d_in[0];
    const int*  Mask = (const int*)d_in[1];
    const float* Wq  = (const float*)d_in[2];
    const float* bq  = (const float*)d_in[3];
    const float* Wk  = (const float*)d_in[4];
    const float* bk  = (const float*)d_in[5];
    const float* Wv  = (const float*)d_in[6];
    const float* bv  = (const float*)d_in[7];
    const float* Wr  = (const float*)d_in[8];
    const float* br  = (const float*)d_in[9];

    constexpr int N = 512, C = 1280;
    constexpr long MN = 32768;   // B*N

    char* ws = (char*)d_ws;
    unsigned short* xb = (unsigned short*)ws;                         // MN*C bf16 (later: att)
    unsigned short* Wt = (unsigned short*)(ws + 83886080);            // 4*C*C bf16
    unsigned short* Q  = (unsigned short*)(ws + 83886080 + 13107200); // MN*C
    unsigned short* Km = Q + 41943040;
    unsigned short* VtD = Km + 41943040;                              // Vt[b][c][m] (written by QKV g==2)
    unsigned short* Sp = VtD + 41943040;                              // B*N*N
    unsigned short* Pt = Sp + 16777216;                               // B*N*N
    unsigned short* att = xb;   // alias: xb dead after QKV GEMMs

    const float scale = 0.02795084971874737f;   // 1/sqrt(1280)

    transpose_w<<<dim3(20, 20, 4), 256, 0, stream>>>(Wq, Wk, Wv, Wr, Wt);
    cast_x<<<dim3(20480), 256, 0, stream>>>(x, xb, MN * C);

    // fused QKV projections: M=32768, N=3x1280, K=1280; tn/5 selects group.
    // Group 2 (V) writes directly transposed into VtD (slot 2 = Q + 2*sC).
    gemm256<0, 1><<<dim3(15, 128, 1), 512, 0, stream>>>(xb, Wt, (void*)Q, bq, bk, bv,
        nullptr, C, C, C, C, 0, 1638400L, 41943040L, 0, 0.f);

    // scores: S'[b][i][j] = scale * (Q[b][i] . K[b][j]), masked
    gemm256<1, 0><<<dim3(2, 2, 64), 512, 0, stream>>>(Q, Km, (void*)Sp, nullptr, nullptr, nullptr,
        Mask, C, C, C, N, (long)N * C, (long)N * C, (long)N * N, (long)N * N, scale);

    // softmax rows + transposed store Pt[b][n][m]
    softmax_t<<<dim3(8, 64), 256, 0, stream>>>(Sp, Pt);

    // att[b][n][c] = sum_m Pt[b][n][m] * VtD[b][c][m]   (M=512, N=1280, K=512)
    gemm256<2, 0><<<dim3(5, 2, 64), 512, 0, stream>>>(Pt, VtD, (void*)att, nullptr, nullptr, nullptr,
        nullptr, N, N, N, C, (long)N * N, (long)C * N, (long)N * C, 0, 0.f);

    // out = att @ Wr + br   (f32)
    gemm256<3, 0><<<dim3(5, 128, 1), 512, 0, stream>>>(att, Wt + 3 * 1638400, d_out, br, nullptr, nullptr,
        nullptr, C, C, C, C, 0, 0, 0, 0, 0.f);
}

// Round 13
// 663.101 us; speedup vs baseline: 1.1209x; 1.1209x over previous
//
#include <hip/hip_runtime.h>
#include <hip/hip_bf16.h>

#define DI __device__ __forceinline__

typedef __attribute__((ext_vector_type(8))) short short8;
typedef __attribute__((ext_vector_type(4))) float f32x4;

DI unsigned short f2bf(float f) {
    union { float f; unsigned int u; } v; v.f = f;
    unsigned int r = v.u + 0x7FFFu + ((v.u >> 16) & 1u);
    return (unsigned short)(r >> 16);
}
DI float bf2f(unsigned short h) {
    union { unsigned int u; float f; } v; v.u = ((unsigned int)h) << 16;
    return v.f;
}

#define GLD16(g, l) __builtin_amdgcn_global_load_lds( \
    (const __attribute__((address_space(1))) void*)(g), \
    (__attribute__((address_space(3))) void*)(l), 16, 0, 0)

// ---------------------------------------------------------------------------
// 256x256 4-phase NT GEMM, BK=64, 8 waves (2Mx4N), 128KiB LDS.
// C[i][j] = sum_k A[i][k] * Bt[j][k]
// Core schedule = r11 (verified 697us best): per phase {12 ds_reads ->
// compiler-interleaved 32 MFMA (setprio) -> vmcnt(8) -> barrier}; peel
// drains 8->4->0.  Swizzle LDS[r][p] = G[r][p ^ ((r>>1)&3)] (conflict-free).
// XCD chunking (bijective, nwg%8==0): lin -> (lin&7)*(nwg/8)+(lin>>3).
// NT full-line stores for write-once outputs.
// QKV group 2 (V) writes output DIRECTLY TRANSPOSED as Vt[b][c][m] (fused
// transpose_v).  r13 FIX vs r12: the Vt read-back now uses the EPI0 store
// pattern (row=rr*16+(tid>>5), ch=tid&31 -> one instruction's lanes write
// contiguous 16B chunks, 4 lanes/64B line).  r12 gave each THREAD 128
// contiguous bytes via 8 separate 16B NT stores -> within one instruction
// lanes were 128B apart -> half-line NT writes -> WRITE_SIZE 505MB (2x).
// EPI: 0 = +bias->bf16(NT), 1 = *scale+mask->bf16, 2 = bf16, 3 = +bias->f32(NT)
// QKV=1: tn in [0,15); g = tn/5 selects Bt/Cout/bias; g==2 -> Vt epilogue.
// Requires: M%256==0, N%256==0, K%128==0, K>=256.
// ---------------------------------------------------------------------------
template<int EPI, int QKV>
__global__ __launch_bounds__(512, 2) void gemm256(
    const unsigned short* __restrict__ A, const unsigned short* __restrict__ Bt,
    void* __restrict__ Cout, const float* __restrict__ bias,
    const float* __restrict__ bias1, const float* __restrict__ bias2,
    const int* __restrict__ mask, int K, int lda, int ldb, int ldc,
    long sA, long sB, long sC, long sM, float scale)
{
    __shared__ unsigned short lds[65536];   // 128 KiB

    // XCD-chunked bijective remap of the flattened grid (nwg % 8 == 0)
    const unsigned gx = gridDim.x, gy = gridDim.y;
    unsigned lin = blockIdx.x + gx * (blockIdx.y + gy * blockIdx.z);
    const unsigned nwg = gx * gy * gridDim.z;
    lin = (lin & 7u) * (nwg >> 3) + (lin >> 3);
    int tn = lin % gx;
    const int tm = (lin / gx) % gy;
    const int z = lin / (gx * gy);

    int gsel = 0;
    if (QKV) {
        gsel = tn / 5; tn -= gsel * 5;
        Bt += (size_t)gsel * sB;
        Cout = (void*)((unsigned short*)Cout + (size_t)gsel * sC);
        if (gsel == 1) bias = bias1; else if (gsel == 2) bias = bias2;
    }

    const unsigned short* Ab = A + (long)z * sA + (size_t)(tm * 256) * lda;
    const unsigned short* Bb = Bt + (QKV ? 0 : (long)z * sB) + (size_t)(tn * 256) * ldb;

    const int tid = threadIdx.x, wave = tid >> 6, l = tid & 63;
    const int wr = wave >> 2, wc = wave & 3;    // 2 x 4 wave grid

    const int srow = wave * 32 + (l >> 2);
    const int schunk = ((l & 3) ^ ((l >> 3) & 3)) * 8;
    const unsigned short* agS = Ab + (size_t)srow * lda + schunk;
    const unsigned short* bgS = Bb + (size_t)srow * ldb + schunk;
    unsigned short* ldsA0 = &lds[wave * 1024];
    unsigned short* ldsB0 = &lds[8192 + wave * 1024];

    const int rl = l & 15;
    const int cl8 = ((l >> 4) ^ ((l >> 1) & 3)) * 8;
    const int aoff = (wr * 128 + rl) * 32 + cl8;
    const int boff = 8192 + (wc * 64 + rl) * 32 + cl8;

#define REGOFF(buf, h) (((buf) * 2 + (h)) * 16384)
#define SA(t, h, buf) { const unsigned short* g_ = agS + (size_t)((t) * 64 + (h) * 32); \
    GLD16(g_, ldsA0 + REGOFF(buf, h)); \
    GLD16(g_ + (size_t)16 * lda, ldsA0 + REGOFF(buf, h) + 512); }
#define SB(t, h, buf) { const unsigned short* g_ = bgS + (size_t)((t) * 64 + (h) * 32); \
    GLD16(g_, ldsB0 + REGOFF(buf, h)); \
    GLD16(g_ + (size_t)16 * ldb, ldsB0 + REGOFF(buf, h) + 512); }

    f32x4 acc[8][4] = {};

    // One phase: consume region (buf,h) fully (32 MFMA), stage next, 1 barrier.
#define PHASE(buf, h, STG, VMW) { \
    short8 af[8], bfv[4]; \
    _Pragma("unroll") for (int i = 0; i < 4; ++i) \
        af[i] = *(const short8*)&lds[REGOFF(buf, h) + aoff + i * 512]; \
    _Pragma("unroll") for (int n = 0; n < 4; ++n) \
        bfv[n] = *(const short8*)&lds[REGOFF(buf, h) + boff + n * 512]; \
    _Pragma("unroll") for (int i = 4; i < 8; ++i) \
        af[i] = *(const short8*)&lds[REGOFF(buf, h) + aoff + i * 512]; \
    STG; \
    __builtin_amdgcn_s_setprio(1); \
    _Pragma("unroll") for (int i = 0; i < 8; ++i) \
        _Pragma("unroll") for (int n = 0; n < 4; ++n) \
            acc[i][n] = __builtin_amdgcn_mfma_f32_16x16x32_bf16( \
                af[i], bfv[n], acc[i][n], 0, 0, 0); \
    __builtin_amdgcn_s_setprio(0); \
    asm volatile("s_waitcnt " VMW ::: "memory"); \
    __builtin_amdgcn_s_barrier(); \
  }

    // prologue: buf0h0, buf0h1, buf1h0 (12 loads); wait buf0h0 (oldest 4)
    SA(0, 0, 0); SB(0, 0, 0); SA(0, 1, 0); SB(0, 1, 0); SA(1, 0, 1); SB(1, 0, 1);
    asm volatile("s_waitcnt vmcnt(8)" ::: "memory");
    __builtin_amdgcn_s_barrier();

    const int NI = K >> 7;          // iterations, 2 K-tiles (BK=64) each
    for (int j = 0; j < NI - 1; ++j) {
        const int t = 2 * j;
        PHASE(0, 0, SA(t + 1, 1, 1) SB(t + 1, 1, 1), "vmcnt(8)")
        PHASE(0, 1, SA(t + 2, 0, 0) SB(t + 2, 0, 0), "vmcnt(8)")
        PHASE(1, 0, SA(t + 2, 1, 0) SB(t + 2, 1, 0), "vmcnt(8)")
        PHASE(1, 1, SA(t + 3, 0, 1) SB(t + 3, 0, 1), "vmcnt(8)")
    }
    {   // peeled last iteration: stage only tile 2NI-1 h1; drain 8->4->0
        const int t = 2 * (NI - 1);
        PHASE(0, 0, SA(t + 1, 1, 1) SB(t + 1, 1, 1), "vmcnt(8)")
        PHASE(0, 1, ((void)0),                       "vmcnt(4)")
        PHASE(1, 0, ((void)0),                       "vmcnt(0)")
        PHASE(1, 1, ((void)0),                       "vmcnt(0)")
    }
#undef PHASE
#undef SA
#undef SB
#undef REGOFF

    // ---------------- epilogue ----------------
    const long cb = QKV ? 0 : (long)z * sC;
    const int row0 = tm * 256 + wr * 128 + (l >> 4) * 4;
    const int col0 = tn * 256 + wc * 64 + rl;

    if (QKV && gsel == 2) {
        // V group: write DIRECTLY TRANSPOSED as Vt[b][c][m] (b=tm>>1,
        // m_base=(tm&1)*256). Two passes over 128-col halves: transposed LDS
        // dump [c][m], then EPI0-style read-back (lane ch -> contiguous 16B,
        // 4 lanes/64B line -> full-line NT stores).
        float b4[4];
        #pragma unroll
        for (int n = 0; n < 4; ++n) b4[n] = bias[col0 + n * 16];
        unsigned short* vout = (unsigned short*)Cout;
        const int bz = tm >> 1, mb = (tm & 1) * 256;
        #pragma unroll
        for (int hc = 0; hc < 2; ++hc) {
            if ((wc >> 1) == hc) {
                #pragma unroll
                for (int mi = 0; mi < 8; ++mi)
                    #pragma unroll
                    for (int n = 0; n < 4; ++n)
                        #pragma unroll
                        for (int r = 0; r < 4; ++r) {
                            const int lc = (wc & 1) * 64 + n * 16 + rl;
                            const int m  = wr * 128 + mi * 16 + ((l >> 4) << 2) + r;
                            lds[lc * 264 + m] = f2bf(acc[mi][n][r] + b4[n]);
                        }
            }
            __syncthreads();
            #pragma unroll
            for (int rr = 0; rr < 8; ++rr) {
                const int row = rr * 16 + (tid >> 5);   // c within half
                const int ch = tid & 31;                // 8-ushort chunk of m
                short8 vv = *(const short8*)&lds[row * 264 + ch * 8];
                __builtin_nontemporal_store(vv,
                    (short8*)&vout[(size_t)bz * 655360
                        + (size_t)(tn * 256 + hc * 128 + row) * 512 + mb + ch * 8]);
            }
            __syncthreads();
        }
    } else if (EPI == 0) {
        // LDS-transpose + 16B nontemporal stores (full-line NT, no L3 fill)
        float b4[4];
        #pragma unroll
        for (int n = 0; n < 4; ++n) b4[n] = bias[col0 + n * 16];
        unsigned short* gout = (unsigned short*)Cout;
        #pragma unroll
        for (int half = 0; half < 2; ++half) {
            if (wr == half) {
                #pragma unroll
                for (int mi = 0; mi < 8; ++mi)
                    #pragma unroll
                    for (int n = 0; n < 4; ++n)
                        #pragma unroll
                        for (int r = 0; r < 4; ++r) {
                            const int lr = mi * 16 + ((l >> 4) << 2) + r;
                            const int lc = wc * 64 + n * 16 + rl;
                            lds[lr * 264 + lc] = f2bf(acc[mi][n][r] + b4[n]);
                        }
            }
            __syncthreads();
            const long rbase = (long)(tm * 256 + half * 128);
            #pragma unroll
            for (int rr = 0; rr < 8; ++rr) {
                const int row = rr * 16 + (tid >> 5);
                const int ch = tid & 31;
                short8 vv = *(const short8*)&lds[row * 264 + ch * 8];
                __builtin_nontemporal_store(vv,
                    (short8*)&gout[(rbase + row) * (size_t)ldc + tn * 256 + ch * 8]);
            }
            __syncthreads();
        }
    } else {
        #pragma unroll
        for (int mi = 0; mi < 8; ++mi) {
            #pragma unroll
            for (int n = 0; n < 4; ++n) {
                #pragma unroll
                for (int r = 0; r < 4; ++r) {
                    const int row = row0 + mi * 16 + r;
                    const int col = col0 + n * 16;
                    float v = acc[mi][n][r];
                    if (EPI == 3) v += bias[col];
                    if (EPI == 1) {
                        v *= scale;
                        if (mask[(long)z * sM + (long)row * ldc + col] == 0)
                            v = -1e20f * scale;
                    }
                    if (EPI == 3)   // f32: 16 lanes x 4B = full 64B line -> NT ok
                        __builtin_nontemporal_store(v, &((float*)Cout)[cb + (long)row * ldc + col]);
                    else
                        ((unsigned short*)Cout)[cb + (long)row * ldc + col] = f2bf(v);
                }
            }
        }
    }
}

// ---------------------------------------------------------------------------
// Transpose+cast the four 1280x1280 f32 weights -> Wt[j][k] bf16
// ---------------------------------------------------------------------------
__global__ void transpose_w(const float* __restrict__ Wq, const float* __restrict__ Wk,
                            const float* __restrict__ Wv, const float* __restrict__ Wr,
                            unsigned short* __restrict__ Wt)
{
    const float* W = blockIdx.z == 0 ? Wq : blockIdx.z == 1 ? Wk : blockIdx.z == 2 ? Wv : Wr;
    unsigned short* dst = Wt + (size_t)blockIdx.z * 1280 * 1280;
    __shared__ float T[64][65];
    const int j0 = blockIdx.x * 64, k0 = blockIdx.y * 64;
    const int tid = threadIdx.x;
    for (int it = 0; it < 16; ++it) {
        int idx = it * 256 + tid;
        int r = idx >> 6, c = idx & 63;
        T[r][c] = W[(size_t)(k0 + r) * 1280 + j0 + c];
    }
    __syncthreads();
    for (int it = 0; it < 16; ++it) {
        int idx = it * 256 + tid;
        int r = idx >> 6, c = idx & 63;
        dst[(size_t)(j0 + r) * 1280 + k0 + c] = f2bf(T[c][r]);
    }
}

// ---------------------------------------------------------------------------
// Cast x f32 -> bf16, vectorized
// ---------------------------------------------------------------------------
__global__ void cast_x(const float* __restrict__ x, unsigned short* __restrict__ xb, long n)
{
    long i = ((long)blockIdx.x * 256 + threadIdx.x) * 8;
    if (i + 8 > n) return;
    const float4* p = (const float4*)(x + i);
    float4 a = p[0], b = p[1];
    unsigned short o[8] = { f2bf(a.x), f2bf(a.y), f2bf(a.z), f2bf(a.w),
                            f2bf(b.x), f2bf(b.y), f2bf(b.z), f2bf(b.w) };
    *(short8*)(xb + i) = *(short8*)o;
}

// ---------------------------------------------------------------------------
// Row softmax of scaled+masked scores S'[b][m][n] (bf16) and transposed write
// Pt[b][n][m] = softmax_row(S')[m][n].  One block per (64-row strip, batch).
// ---------------------------------------------------------------------------
#define SMS 514
__global__ void softmax_t(const unsigned short* __restrict__ S, unsigned short* __restrict__ Pt)
{
    __shared__ unsigned short T[64 * SMS];
    __shared__ float rmax[64], rinv[64];
    const int b = blockIdx.y, mb = blockIdx.x * 64;
    const int tid = threadIdx.x, lane = tid & 63, wave = tid >> 6;
    const unsigned short* src = S + ((size_t)b * 512 + mb) * 512;

    for (int rr = 0; rr < 16; ++rr) {
        int r = rr * 4 + wave;
        const unsigned int* s = (const unsigned int*)(src + (size_t)r * 512);
        unsigned int* t = (unsigned int*)&T[r * SMS];
        #pragma unroll
        for (int j = 0; j < 4; ++j) t[lane + j * 64] = s[lane + j * 64];
    }
    __syncthreads();

    {   // row stats: 4 threads per row
        int r = tid >> 2, q = tid & 3;
        const unsigned short* row = &T[r * SMS + q * 128];
        float mx = -3.0e38f;
        for (int i = 0; i < 128; ++i) mx = fmaxf(mx, bf2f(row[i]));
        mx = fmaxf(mx, __shfl_xor(mx, 1));
        mx = fmaxf(mx, __shfl_xor(mx, 2));
        float s = 0.f;
        for (int i = 0; i < 128; ++i) s += expf(bf2f(row[i]) - mx);
        s += __shfl_xor(s, 1);
        s += __shfl_xor(s, 2);
        if (q == 0) { rmax[r] = mx; rinv[r] = 1.0f / s; }
    }
    __syncthreads();

    {   // transposed write: lane -> m, groups of 64 -> n
        int m = tid & 63, nq = tid >> 6;
        float mxm = rmax[m], rim = rinv[m];
        unsigned short* dst = Pt + (size_t)b * 512 * 512 + mb + m;
        for (int it = 0; it < 128; ++it) {
            int n = it * 4 + nq;
            float v = expf(bf2f(T[m * SMS + n]) - mxm) * rim;
            dst[(size_t)n * 512] = f2bf(v);
        }
    }
}

// ---------------------------------------------------------------------------
extern "C" void kernel_launch(void* const* d_in, const int* in_sizes, int n_in,
                              void* d_out, int out_size, void* d_ws, size_t ws_size,
                              hipStream_t stream)
{
    const float* x   = (const float*)d_in[0];
    const int*  Mask = (const int*)d_in[1];
    const float* Wq  = (const float*)d_in[2];
    const float* bq  = (const float*)d_in[3];
    const float* Wk  = (const float*)d_in[4];
    const float* bk  = (const float*)d_in[5];
    const float* Wv  = (const float*)d_in[6];
    const float* bv  = (const float*)d_in[7];
    const float* Wr  = (const float*)d_in[8];
    const float* br  = (const float*)d_in[9];

    constexpr int N = 512, C = 1280;
    constexpr long MN = 32768;   // B*N

    char* ws = (char*)d_ws;
    unsigned short* xb = (unsigned short*)ws;                         // MN*C bf16 (later: att)
    unsigned short* Wt = (unsigned short*)(ws + 83886080);            // 4*C*C bf16
    unsigned short* Q  = (unsigned short*)(ws + 83886080 + 13107200); // MN*C
    unsigned short* Km = Q + 41943040;
    unsigned short* VtD = Km + 41943040;                              // Vt[b][c][m] (written by QKV g==2)
    unsigned short* Sp = VtD + 41943040;                              // B*N*N
    unsigned short* Pt = Sp + 16777216;                               // B*N*N
    unsigned short* att = xb;   // alias: xb dead after QKV GEMMs

    const float scale = 0.02795084971874737f;   // 1/sqrt(1280)

    transpose_w<<<dim3(20, 20, 4), 256, 0, stream>>>(Wq, Wk, Wv, Wr, Wt);
    cast_x<<<dim3(20480), 256, 0, stream>>>(x, xb, MN * C);

    // fused QKV projections: M=32768, N=3x1280, K=1280; tn/5 selects group.
    // Group 2 (V) writes directly transposed into VtD (slot 2 = Q + 2*sC).
    gemm256<0, 1><<<dim3(15, 128, 1), 512, 0, stream>>>(xb, Wt, (void*)Q, bq, bk, bv,
        nullptr, C, C, C, C, 0, 1638400L, 41943040L, 0, 0.f);

    // scores: S'[b][i][j] = scale * (Q[b][i] . K[b][j]), masked
    gemm256<1, 0><<<dim3(2, 2, 64), 512, 0, stream>>>(Q, Km, (void*)Sp, nullptr, nullptr, nullptr,
        Mask, C, C, C, N, (long)N * C, (long)N * C, (long)N * N, (long)N * N, scale);

    // softmax rows + transposed store Pt[b][n][m]
    softmax_t<<<dim3(8, 64), 256, 0, stream>>>(Sp, Pt);

    // att[b][n][c] = sum_m Pt[b][n][m] * VtD[b][c][m]   (M=512, N=1280, K=512)
    gemm256<2, 0><<<dim3(5, 2, 64), 512, 0, stream>>>(Pt, VtD, (void*)att, nullptr, nullptr, nullptr,
        nullptr, N, N, N, C, (long)N * N, (long)C * N, (long)N * C, 0, 0.f);

    // out = att @ Wr + br   (f32)
    gemm256<3, 0><<<dim3(5, 128, 1), 512, 0, stream>>>(att, Wt + 3 * 1638400, d_out, br, nullptr, nullptr,
        nullptr, C, C, C, C, 0, 0, 0, 0, 0.f);
}

// Round 14
// 647.174 us; speedup vs baseline: 1.1484x; 1.0246x over previous
//
#include <hip/hip_runtime.h>
#include <hip/hip_bf16.h>

#define DI __device__ __forceinline__

typedef __attribute__((ext_vector_type(8))) short short8;
typedef __attribute__((ext_vector_type(4))) float f32x4;

DI unsigned short f2bf(float f) {
    union { float f; unsigned int u; } v; v.f = f;
    unsigned int r = v.u + 0x7FFFu + ((v.u >> 16) & 1u);
    return (unsigned short)(r >> 16);
}
DI float bf2f(unsigned short h) {
    union { unsigned int u; float f; } v; v.u = ((unsigned int)h) << 16;
    return v.f;
}

#define GLD16(g, l) __builtin_amdgcn_global_load_lds( \
    (const __attribute__((address_space(1))) void*)(g), \
    (__attribute__((address_space(3))) void*)(l), 16, 0, 0)

// ---------------------------------------------------------------------------
// 256x256 4-phase NT GEMM, BK=64, 8 waves (2Mx4N), 128KiB LDS.  (r13 core,
// verified 663us best.)  C[i][j] = sum_k A[i][k] * Bt[j][k]
// Swizzle LDS[r][p] = G[r][p ^ ((r>>1)&3)] (conflict-free).  XCD chunking
// (bijective, nwg%8==0).  NT full-line stores for write-once outputs.
// QKV group 2 (V) writes output directly transposed as Vt[b][c][m].
// EPI: 0 = +bias->bf16(NT), 2 = bf16, 3 = +bias->f32(NT)
// ---------------------------------------------------------------------------
template<int EPI, int QKV>
__global__ __launch_bounds__(512, 2) void gemm256(
    const unsigned short* __restrict__ A, const unsigned short* __restrict__ Bt,
    void* __restrict__ Cout, const float* __restrict__ bias,
    const float* __restrict__ bias1, const float* __restrict__ bias2,
    int K, int lda, int ldb, int ldc,
    long sA, long sB, long sC)
{
    __shared__ unsigned short lds[65536];   // 128 KiB

    const unsigned gx = gridDim.x, gy = gridDim.y;
    unsigned lin = blockIdx.x + gx * (blockIdx.y + gy * blockIdx.z);
    const unsigned nwg = gx * gy * gridDim.z;
    lin = (lin & 7u) * (nwg >> 3) + (lin >> 3);
    int tn = lin % gx;
    const int tm = (lin / gx) % gy;
    const int z = lin / (gx * gy);

    int gsel = 0;
    if (QKV) {
        gsel = tn / 5; tn -= gsel * 5;
        Bt += (size_t)gsel * sB;
        Cout = (void*)((unsigned short*)Cout + (size_t)gsel * sC);
        if (gsel == 1) bias = bias1; else if (gsel == 2) bias = bias2;
    }

    const unsigned short* Ab = A + (long)z * sA + (size_t)(tm * 256) * lda;
    const unsigned short* Bb = Bt + (QKV ? 0 : (long)z * sB) + (size_t)(tn * 256) * ldb;

    const int tid = threadIdx.x, wave = tid >> 6, l = tid & 63;
    const int wr = wave >> 2, wc = wave & 3;    // 2 x 4 wave grid

    const int srow = wave * 32 + (l >> 2);
    const int schunk = ((l & 3) ^ ((l >> 3) & 3)) * 8;
    const unsigned short* agS = Ab + (size_t)srow * lda + schunk;
    const unsigned short* bgS = Bb + (size_t)srow * ldb + schunk;
    unsigned short* ldsA0 = &lds[wave * 1024];
    unsigned short* ldsB0 = &lds[8192 + wave * 1024];

    const int rl = l & 15;
    const int cl8 = ((l >> 4) ^ ((l >> 1) & 3)) * 8;
    const int aoff = (wr * 128 + rl) * 32 + cl8;
    const int boff = 8192 + (wc * 64 + rl) * 32 + cl8;

#define REGOFF(buf, h) (((buf) * 2 + (h)) * 16384)
#define SA(t, h, buf) { const unsigned short* g_ = agS + (size_t)((t) * 64 + (h) * 32); \
    GLD16(g_, ldsA0 + REGOFF(buf, h)); \
    GLD16(g_ + (size_t)16 * lda, ldsA0 + REGOFF(buf, h) + 512); }
#define SB(t, h, buf) { const unsigned short* g_ = bgS + (size_t)((t) * 64 + (h) * 32); \
    GLD16(g_, ldsB0 + REGOFF(buf, h)); \
    GLD16(g_ + (size_t)16 * ldb, ldsB0 + REGOFF(buf, h) + 512); }

    f32x4 acc[8][4] = {};

#define PHASE(buf, h, STG, VMW) { \
    short8 af[8], bfv[4]; \
    _Pragma("unroll") for (int i = 0; i < 4; ++i) \
        af[i] = *(const short8*)&lds[REGOFF(buf, h) + aoff + i * 512]; \
    _Pragma("unroll") for (int n = 0; n < 4; ++n) \
        bfv[n] = *(const short8*)&lds[REGOFF(buf, h) + boff + n * 512]; \
    _Pragma("unroll") for (int i = 4; i < 8; ++i) \
        af[i] = *(const short8*)&lds[REGOFF(buf, h) + aoff + i * 512]; \
    STG; \
    __builtin_amdgcn_s_setprio(1); \
    _Pragma("unroll") for (int i = 0; i < 8; ++i) \
        _Pragma("unroll") for (int n = 0; n < 4; ++n) \
            acc[i][n] = __builtin_amdgcn_mfma_f32_16x16x32_bf16( \
                af[i], bfv[n], acc[i][n], 0, 0, 0); \
    __builtin_amdgcn_s_setprio(0); \
    asm volatile("s_waitcnt " VMW ::: "memory"); \
    __builtin_amdgcn_s_barrier(); \
  }

    SA(0, 0, 0); SB(0, 0, 0); SA(0, 1, 0); SB(0, 1, 0); SA(1, 0, 1); SB(1, 0, 1);
    asm volatile("s_waitcnt vmcnt(8)" ::: "memory");
    __builtin_amdgcn_s_barrier();

    const int NI = K >> 7;
    for (int j = 0; j < NI - 1; ++j) {
        const int t = 2 * j;
        PHASE(0, 0, SA(t + 1, 1, 1) SB(t + 1, 1, 1), "vmcnt(8)")
        PHASE(0, 1, SA(t + 2, 0, 0) SB(t + 2, 0, 0), "vmcnt(8)")
        PHASE(1, 0, SA(t + 2, 1, 0) SB(t + 2, 1, 0), "vmcnt(8)")
        PHASE(1, 1, SA(t + 3, 0, 1) SB(t + 3, 0, 1), "vmcnt(8)")
    }
    {
        const int t = 2 * (NI - 1);
        PHASE(0, 0, SA(t + 1, 1, 1) SB(t + 1, 1, 1), "vmcnt(8)")
        PHASE(0, 1, ((void)0),                       "vmcnt(4)")
        PHASE(1, 0, ((void)0),                       "vmcnt(0)")
        PHASE(1, 1, ((void)0),                       "vmcnt(0)")
    }
#undef PHASE
#undef SA
#undef SB
#undef REGOFF

    // ---------------- epilogue ----------------
    const long cb = QKV ? 0 : (long)z * sC;
    const int row0 = tm * 256 + wr * 128 + (l >> 4) * 4;
    const int col0 = tn * 256 + wc * 64 + rl;

    if (QKV && gsel == 2) {
        // V: write directly transposed as Vt[b][c][m]; EPI0-style NT read-back
        float b4[4];
        #pragma unroll
        for (int n = 0; n < 4; ++n) b4[n] = bias[col0 + n * 16];
        unsigned short* vout = (unsigned short*)Cout;
        const int bz = tm >> 1, mb = (tm & 1) * 256;
        #pragma unroll
        for (int hc = 0; hc < 2; ++hc) {
            if ((wc >> 1) == hc) {
                #pragma unroll
                for (int mi = 0; mi < 8; ++mi)
                    #pragma unroll
                    for (int n = 0; n < 4; ++n)
                        #pragma unroll
                        for (int r = 0; r < 4; ++r) {
                            const int lc = (wc & 1) * 64 + n * 16 + rl;
                            const int m  = wr * 128 + mi * 16 + ((l >> 4) << 2) + r;
                            lds[lc * 264 + m] = f2bf(acc[mi][n][r] + b4[n]);
                        }
            }
            __syncthreads();
            #pragma unroll
            for (int rr = 0; rr < 8; ++rr) {
                const int row = rr * 16 + (tid >> 5);
                const int ch = tid & 31;
                short8 vv = *(const short8*)&lds[row * 264 + ch * 8];
                __builtin_nontemporal_store(vv,
                    (short8*)&vout[(size_t)bz * 655360
                        + (size_t)(tn * 256 + hc * 128 + row) * 512 + mb + ch * 8]);
            }
            __syncthreads();
        }
    } else if (EPI == 0) {
        float b4[4];
        #pragma unroll
        for (int n = 0; n < 4; ++n) b4[n] = bias[col0 + n * 16];
        unsigned short* gout = (unsigned short*)Cout;
        #pragma unroll
        for (int half = 0; half < 2; ++half) {
            if (wr == half) {
                #pragma unroll
                for (int mi = 0; mi < 8; ++mi)
                    #pragma unroll
                    for (int n = 0; n < 4; ++n)
                        #pragma unroll
                        for (int r = 0; r < 4; ++r) {
                            const int lr = mi * 16 + ((l >> 4) << 2) + r;
                            const int lc = wc * 64 + n * 16 + rl;
                            lds[lr * 264 + lc] = f2bf(acc[mi][n][r] + b4[n]);
                        }
            }
            __syncthreads();
            const long rbase = (long)(tm * 256 + half * 128);
            #pragma unroll
            for (int rr = 0; rr < 8; ++rr) {
                const int row = rr * 16 + (tid >> 5);
                const int ch = tid & 31;
                short8 vv = *(const short8*)&lds[row * 264 + ch * 8];
                __builtin_nontemporal_store(vv,
                    (short8*)&gout[(rbase + row) * (size_t)ldc + tn * 256 + ch * 8]);
            }
            __syncthreads();
        }
    } else {
        #pragma unroll
        for (int mi = 0; mi < 8; ++mi) {
            #pragma unroll
            for (int n = 0; n < 4; ++n) {
                #pragma unroll
                for (int r = 0; r < 4; ++r) {
                    const int row = row0 + mi * 16 + r;
                    const int col = col0 + n * 16;
                    float v = acc[mi][n][r];
                    if (EPI == 3) v += bias[col];
                    if (EPI == 3)
                        __builtin_nontemporal_store(v, &((float*)Cout)[cb + (long)row * ldc + col]);
                    else
                        ((unsigned short*)Cout)[cb + (long)row * ldc + col] = f2bf(v);
                }
            }
        }
    }
}

// ---------------------------------------------------------------------------
// Fused scores + masked softmax: Pt[b][n][m] = softmax_n(scale*Q[b][m].K[b][n],
// mask) -- BM=128 (m), BN=512 (full n), BK=32, rotation-3 (40KB/slot, 120KB),
// 8 waves 2Mx4N (per-wave 64x128, acc[4][8]).  Same swizzle/staging idioms as
// gemm256.  Softmax rows are complete inside the block: per-row max/sum via
// shfl_xor(1,2,4,8) + cross-wave LDS reduce; transposed bf16 write via LDS
// (2 column-halves, [256][132] pad -> dump bank=rl conflict-free, read b128
// 2-way=free).  Eliminates Sp + softmax_t (64MB traffic + a dispatch).
// ---------------------------------------------------------------------------
__global__ __launch_bounds__(512, 2) void qk_softmax(
    const unsigned short* __restrict__ Q, const unsigned short* __restrict__ Km,
    unsigned short* __restrict__ Pt, const int* __restrict__ mask, float scale)
{
    __shared__ unsigned short lds[65536];   // staging uses 61440; epilogue reuses

    const unsigned gx = gridDim.x;                      // 4 m-tiles
    unsigned lin = blockIdx.x + gx * blockIdx.z;
    const unsigned nwg = gx * gridDim.z;                // 256, %8==0
    lin = (lin & 7u) * (nwg >> 3) + (lin >> 3);
    const int tm = lin % gx;
    const int z  = lin / gx;

    const unsigned short* Ab = Q  + (size_t)z * 655360 + (size_t)(tm * 128) * 1280;
    const unsigned short* Bb = Km + (size_t)z * 655360;

    const int tid = threadIdx.x, wave = tid >> 6, l = tid & 63;
    const int wr = wave >> 2, wc = wave & 3;            // 2M x 4N
    const int rl = l & 15, lh = l >> 4;

    const int schunk = ((l & 3) ^ ((l >> 3) & 3)) * 8;
    const unsigned short* agS = Ab + (size_t)(wave * 16 + (l >> 2)) * 1280 + schunk;
    const unsigned short* bgS = Bb + (size_t)(wave * 16 + (l >> 2)) * 1280 + schunk;
    unsigned short* ldsA = &lds[wave * 512];
    unsigned short* ldsB = &lds[4096 + wave * 512];

    const int cl8 = ((l >> 4) ^ ((l >> 1) & 3)) * 8;
    const int aoff = (wr * 64 + rl) * 32 + cl8;         // A: 128 rows
    const int boff = 4096 + (wc * 128 + rl) * 32 + cl8; // B: 512 rows

#define SLOT(s) ((s) * 20480)
#define SAQ(t, s) { GLD16(agS + (size_t)(t) * 32, ldsA + SLOT(s)); }
#define SBQ(t, s) { const unsigned short* g_ = bgS + (size_t)(t) * 32; \
    GLD16(g_,                       ldsB + SLOT(s)); \
    GLD16(g_ + (size_t)128 * 1280,  ldsB + SLOT(s) + 4096); \
    GLD16(g_ + (size_t)256 * 1280,  ldsB + SLOT(s) + 8192); \
    GLD16(g_ + (size_t)384 * 1280,  ldsB + SLOT(s) + 12288); }

    f32x4 acc[4][8] = {};

    // prologue: slots 0,1 (10 loads); drain slot0 (leave slot1's 5)
    SAQ(0, 0) SBQ(0, 0) SAQ(1, 1) SBQ(1, 1)
    asm volatile("s_waitcnt vmcnt(5)" ::: "memory");
    __builtin_amdgcn_s_barrier();

    int g0 = 0;
    for (int t = 0; t < 40; ++t) {                      // K=1280, BK=32
        const int base = g0 * 20480;
        int g2 = g0 + 2; if (g2 >= 3) g2 -= 3;
        const bool stg = (t + 2 < 40);
        short8 af[4], bfv[8];
        #pragma unroll
        for (int i = 0; i < 4; ++i) af[i] = *(const short8*)&lds[base + aoff + i * 512];
        #pragma unroll
        for (int n = 0; n < 8; ++n) bfv[n] = *(const short8*)&lds[base + boff + n * 512];
        if (stg) { SAQ(t + 2, g2) SBQ(t + 2, g2) }
        __builtin_amdgcn_s_setprio(1);
        #pragma unroll
        for (int i = 0; i < 4; ++i)
            #pragma unroll
            for (int n = 0; n < 8; ++n)
                acc[i][n] = __builtin_amdgcn_mfma_f32_16x16x32_bf16(af[i], bfv[n], acc[i][n], 0, 0, 0);
        __builtin_amdgcn_s_setprio(0);
        if (stg) { asm volatile("s_waitcnt vmcnt(5)" ::: "memory"); }
        else     { asm volatile("s_waitcnt vmcnt(0)" ::: "memory"); }
        __builtin_amdgcn_s_barrier();
        g0 = (g0 == 2) ? 0 : g0 + 1;
    }
#undef SAQ
#undef SBQ
#undef SLOT

    // ---- scale + mask (coalesced: lanes vary col) ----
    const int col0 = wc * 128 + rl;
    {
        const int* mb = mask + (size_t)z * 262144;
        #pragma unroll
        for (int mi = 0; mi < 4; ++mi)
            #pragma unroll
            for (int r = 0; r < 4; ++r) {
                const int m = tm * 128 + wr * 64 + mi * 16 + lh * 4 + r;
                const int* mp = mb + (size_t)m * 512 + col0;
                #pragma unroll
                for (int nj = 0; nj < 8; ++nj) {
                    float x = acc[mi][nj][r] * scale;
                    if (mp[nj * 16] == 0) x = -2.795084971874737e18f;  // -1e20*scale
                    acc[mi][nj][r] = x;
                }
            }
    }
    // ---- row max: 8 regs -> 16 lanes (shfl) -> 4 waves (LDS) ----
    float* red = (float*)lds;                           // [4][128] floats
    float rmx[4][4], rinv[4][4];
    #pragma unroll
    for (int mi = 0; mi < 4; ++mi)
        #pragma unroll
        for (int r = 0; r < 4; ++r) {
            float mx = acc[mi][0][r];
            #pragma unroll
            for (int nj = 1; nj < 8; ++nj) mx = fmaxf(mx, acc[mi][nj][r]);
            mx = fmaxf(mx, __shfl_xor(mx, 1));
            mx = fmaxf(mx, __shfl_xor(mx, 2));
            mx = fmaxf(mx, __shfl_xor(mx, 4));
            mx = fmaxf(mx, __shfl_xor(mx, 8));
            if (rl == 0) red[wc * 128 + wr * 64 + mi * 16 + lh * 4 + r] = mx;
        }
    __syncthreads();
    #pragma unroll
    for (int mi = 0; mi < 4; ++mi)
        #pragma unroll
        for (int r = 0; r < 4; ++r) {
            const int rowl = wr * 64 + mi * 16 + lh * 4 + r;
            rmx[mi][r] = fmaxf(fmaxf(red[rowl], red[128 + rowl]),
                               fmaxf(red[256 + rowl], red[384 + rowl]));
        }
    __syncthreads();
    // ---- exp + row sum ----
    #pragma unroll
    for (int mi = 0; mi < 4; ++mi)
        #pragma unroll
        for (int r = 0; r < 4; ++r) {
            float s = 0.f;
            #pragma unroll
            for (int nj = 0; nj < 8; ++nj) {
                float e = __expf(acc[mi][nj][r] - rmx[mi][r]);
                acc[mi][nj][r] = e; s += e;
            }
            s += __shfl_xor(s, 1); s += __shfl_xor(s, 2);
            s += __shfl_xor(s, 4); s += __shfl_xor(s, 8);
            if (rl == 0) red[wc * 128 + wr * 64 + mi * 16 + lh * 4 + r] = s;
        }
    __syncthreads();
    #pragma unroll
    for (int mi = 0; mi < 4; ++mi)
        #pragma unroll
        for (int r = 0; r < 4; ++r) {
            const int rowl = wr * 64 + mi * 16 + lh * 4 + r;
            rinv[mi][r] = 1.0f / (red[rowl] + red[128 + rowl] + red[256 + rowl] + red[384 + rowl]);
        }
    // ---- transposed write Pt[n][m] via LDS, two 256-col halves ----
    unsigned short* Pb = Pt + (size_t)z * 262144 + (size_t)tm * 128;
    #pragma unroll
    for (int nh = 0; nh < 2; ++nh) {
        __syncthreads();
        if ((wc >> 1) == nh) {
            #pragma unroll
            for (int mi = 0; mi < 4; ++mi)
                #pragma unroll
                for (int nj = 0; nj < 8; ++nj)
                    #pragma unroll
                    for (int r = 0; r < 4; ++r) {
                        const int cl = (wc & 1) * 128 + nj * 16 + rl;
                        const int rowl = wr * 64 + mi * 16 + lh * 4 + r;
                        lds[cl * 132 + rowl] = f2bf(acc[mi][nj][r] * rinv[mi][r]);
                    }
        }
        __syncthreads();
        #pragma unroll
        for (int rr = 0; rr < 8; ++rr) {
            const int nl = rr * 32 + (tid >> 4);
            const int ch = tid & 15;
            short8 vv = *(const short8*)&lds[nl * 132 + ch * 8];
            *(short8*)&Pb[(size_t)(nh * 256 + nl) * 512 + ch * 8] = vv;
        }
    }
}

// ---------------------------------------------------------------------------
// Transpose+cast the four 1280x1280 f32 weights -> Wt[j][k] bf16
// ---------------------------------------------------------------------------
__global__ void transpose_w(const float* __restrict__ Wq, const float* __restrict__ Wk,
                            const float* __restrict__ Wv, const float* __restrict__ Wr,
                            unsigned short* __restrict__ Wt)
{
    const float* W = blockIdx.z == 0 ? Wq : blockIdx.z == 1 ? Wk : blockIdx.z == 2 ? Wv : Wr;
    unsigned short* dst = Wt + (size_t)blockIdx.z * 1280 * 1280;
    __shared__ float T[64][65];
    const int j0 = blockIdx.x * 64, k0 = blockIdx.y * 64;
    const int tid = threadIdx.x;
    for (int it = 0; it < 16; ++it) {
        int idx = it * 256 + tid;
        int r = idx >> 6, c = idx & 63;
        T[r][c] = W[(size_t)(k0 + r) * 1280 + j0 + c];
    }
    __syncthreads();
    for (int it = 0; it < 16; ++it) {
        int idx = it * 256 + tid;
        int r = idx >> 6, c = idx & 63;
        dst[(size_t)(j0 + r) * 1280 + k0 + c] = f2bf(T[c][r]);
    }
}

// ---------------------------------------------------------------------------
// Cast x f32 -> bf16, vectorized
// ---------------------------------------------------------------------------
__global__ void cast_x(const float* __restrict__ x, unsigned short* __restrict__ xb, long n)
{
    long i = ((long)blockIdx.x * 256 + threadIdx.x) * 8;
    if (i + 8 > n) return;
    const float4* p = (const float4*)(x + i);
    float4 a = p[0], b = p[1];
    unsigned short o[8] = { f2bf(a.x), f2bf(a.y), f2bf(a.z), f2bf(a.w),
                            f2bf(b.x), f2bf(b.y), f2bf(b.z), f2bf(b.w) };
    *(short8*)(xb + i) = *(short8*)o;
}

// ---------------------------------------------------------------------------
extern "C" void kernel_launch(void* const* d_in, const int* in_sizes, int n_in,
                              void* d_out, int out_size, void* d_ws, size_t ws_size,
                              hipStream_t stream)
{
    const float* x   = (const float*)d_in[0];
    const int*  Mask = (const int*)d_in[1];
    const float* Wq  = (const float*)d_in[2];
    const float* bq  = (const float*)d_in[3];
    const float* Wk  = (const float*)d_in[4];
    const float* bk  = (const float*)d_in[5];
    const float* Wv  = (const float*)d_in[6];
    const float* bv  = (const float*)d_in[7];
    const float* Wr  = (const float*)d_in[8];
    const float* br  = (const float*)d_in[9];

    constexpr int N = 512, C = 1280;
    constexpr long MN = 32768;   // B*N

    char* ws = (char*)d_ws;
    unsigned short* xb = (unsigned short*)ws;                         // MN*C bf16 (later: att)
    unsigned short* Wt = (unsigned short*)(ws + 83886080);            // 4*C*C bf16
    unsigned short* Q  = (unsigned short*)(ws + 83886080 + 13107200); // MN*C
    unsigned short* Km = Q + 41943040;
    unsigned short* VtD = Km + 41943040;                              // Vt[b][c][m] (QKV g==2)
    unsigned short* Pt = VtD + 41943040;                              // B*N*N
    unsigned short* att = xb;   // alias: xb dead after QKV GEMMs

    const float scale = 0.02795084971874737f;   // 1/sqrt(1280)

    transpose_w<<<dim3(20, 20, 4), 256, 0, stream>>>(Wq, Wk, Wv, Wr, Wt);
    cast_x<<<dim3(20480), 256, 0, stream>>>(x, xb, MN * C);

    // fused QKV projections: M=32768, N=3x1280, K=1280; tn/5 selects group.
    // Group 2 (V) writes directly transposed into VtD (slot 2 = Q + 2*sC).
    gemm256<0, 1><<<dim3(15, 128, 1), 512, 0, stream>>>(xb, Wt, (void*)Q, bq, bk, bv,
        C, C, C, C, 0, 1638400L, 41943040L);

    // fused scores+softmax: Pt[b][n][m] = softmax(scale*Q.K^T, mask)
    qk_softmax<<<dim3(4, 1, 64), 512, 0, stream>>>(Q, Km, Pt, Mask, scale);

    // att[b][n][c] = sum_m Pt[b][n][m] * VtD[b][c][m]   (M=512, N=1280, K=512)
    gemm256<2, 0><<<dim3(5, 2, 64), 512, 0, stream>>>(Pt, VtD, (void*)att, nullptr, nullptr, nullptr,
        N, N, N, C, (long)N * N, (long)C * N, (long)N * C);

    // out = att @ Wr + br   (f32)
    gemm256<3, 0><<<dim3(5, 128, 1), 512, 0, stream>>>(att, Wt + 3 * 1638400, d_out, br, nullptr, nullptr,
        C, C, C, C, 0, 0, 0);
}